// Round 7
// baseline (495.956 us; speedup 1.0000x reference)
//
#include <hip/hip_runtime.h>
#include <hip/hip_cooperative_groups.h>
#include <stdint.h>

namespace cg = cooperative_groups;

#define NBATCH 16
#define NOBS   16384     // MAX_DIM (per batch row)
#define NELEM  (NBATCH * NOBS)
#define NSUP   8192
#define NQRY   4096
#define NTOT   12288
#define DIMV   128       // 512 floats = 128 float4
#define NBINS  4096
#define BINSHIFT 11      // 23-bit key >> 11 -> 12-bit bin (avg 4/bin)

typedef float f32x4 __attribute__((ext_vector_type(4)));

__device__ __forceinline__ uint32_t rotl32(uint32_t x, int r) {
  return (x << r) | (x >> (32 - r));
}

// Exact JAX threefry2x32 with key = (0, 42). Verified vs Random123 KAT.
__device__ __forceinline__ void threefry2x32_k42(uint32_t& x0, uint32_t& x1) {
  const uint32_t ks0 = 0u;
  const uint32_t ks1 = 42u;
  const uint32_t ks2 = 0u ^ 42u ^ 0x1BD11BDAu;
  x0 += ks0; x1 += ks1;
#define TF_ROUND(r) { x0 += x1; x1 = rotl32(x1, (r)); x1 ^= x0; }
  TF_ROUND(13) TF_ROUND(15) TF_ROUND(26) TF_ROUND(6)
  x0 += ks1; x1 += ks2 + 1u;
  TF_ROUND(17) TF_ROUND(29) TF_ROUND(16) TF_ROUND(24)
  x0 += ks2; x1 += ks0 + 2u;
  TF_ROUND(13) TF_ROUND(15) TF_ROUND(26) TF_ROUND(6)
  x0 += ks0; x1 += ks1 + 3u;
  TF_ROUND(17) TF_ROUND(29) TF_ROUND(16) TF_ROUND(24)
  x0 += ks1; x1 += ks2 + 4u;
  TF_ROUND(13) TF_ROUND(15) TF_ROUND(26) TF_ROUND(6)
  x0 += ks2; x1 += ks0 + 5u;
#undef TF_ROUND
}

// Partitionable threefry (jax default): counter = (0, flat_index),
// output = x0 ^ x1; key = bits >> 9 (23 mantissa bits, monotone in score).
// [CONFIRMED bit-exact rounds 2-6]
__device__ __forceinline__ uint32_t jax_key(uint32_t f) {
  uint32_t x0 = 0u, x1 = f;
  threefry2x32_k42(x0, x1);
  return (x0 ^ x1) >> 9;
}

// Packed within-bin comparator: (key_low11 << 14) | (16383 - idx).
// Within one bin, q earlier-ranked than m  <=>  packed_q > packed_m.
__device__ __forceinline__ uint32_t pack_cmp(uint32_t key, uint32_t idx_in_row) {
  return ((key & 0x7FFu) << 14) | (16383u - idx_in_row);
}

// Single cooperative setup kernel: zero-hist -> histogram -> per-batch
// suffix scan -> bucket scatter -> exact rank -> rmat[idx][b] (u16).
// 1024 blocks x 256 thr (4 blocks/CU, co-resident; ~1KB LDS).
__global__ void __launch_bounds__(256)
k_setup(uint32_t* __restrict__ hist, uint32_t* __restrict__ base,
        uint32_t* __restrict__ cursor, uint32_t* __restrict__ bucket,
        uint16_t* __restrict__ rmat) {
  cg::grid_group grid = cg::this_grid();
  __shared__ uint32_t csum[256];

  const uint32_t g = blockIdx.x * 256 + threadIdx.x;   // 0..NELEM-1

  // ---- phase 0: zero hist (NBATCH*NBINS = 65536 entries) ----
  if (g < NBATCH * NBINS) hist[g] = 0u;
  grid.sync();

  // ---- phase 1: per-batch histogram (key stays in registers) ----
  const uint32_t b   = g >> 14;
  const uint32_t idx = g & 16383u;
  const uint32_t key = jax_key(g);
  const uint32_t bin = key >> BINSHIFT;
  atomicAdd(&hist[b * NBINS + bin], 1u);
  grid.sync();

  // ---- phase 2: suffix scan, blocks 0..15 (one per batch) ----
  if (blockIdx.x < NBATCH) {
    const int sb = blockIdx.x;
    const int t  = threadIdx.x;          // owns bins [t*16, t*16+16)
    uint32_t c[16];
    uint32_t tot = 0;
    const uint32_t* hrow = hist + sb * NBINS + t * 16;
#pragma unroll
    for (int j = 0; j < 16; ++j) { c[j] = hrow[j]; tot += c[j]; }
    csum[t] = tot;
    __syncthreads();
    // Hillis-Steele inclusive SUFFIX scan over 256 chunk totals
    uint32_t v = tot;
    for (int off = 1; off < 256; off <<= 1) {
      const uint32_t add = (t + off < 256) ? csum[t + off] : 0u;
      __syncthreads();
      v += add;
      csum[t] = v;
      __syncthreads();
    }
    const uint32_t higher = (t + 1 < 256) ? csum[t + 1] : 0u;
    // base[bin] = #elements in strictly-higher bins
    uint32_t run = higher;
    uint32_t* bo = base   + sb * NBINS + t * 16;
    uint32_t* co = cursor + sb * NBINS + t * 16;
#pragma unroll
    for (int j = 15; j >= 0; --j) {
      bo[j] = run; co[j] = run;
      run += c[j];
    }
  }
  grid.sync();

  // ---- phase 3: bucket scatter ----
  const uint32_t me  = pack_cmp(key, idx);
  const uint32_t pos = atomicAdd(&cursor[b * NBINS + bin], 1u);
  bucket[b * NOBS + pos] = me;
  grid.sync();

  // ---- phase 4: exact rank -> rmat ----
  const uint32_t lob = base[b * NBINS + bin];
  const uint32_t n   = hist[b * NBINS + bin];
  const uint32_t* bk = bucket + b * NOBS + lob;
  uint32_t cnt = 0;
  for (uint32_t q = 0; q < n; ++q) cnt += (bk[q] > me) ? 1u : 0u;
  rmat[idx * NBATCH + b] = (uint16_t)(lob + cnt);
}

// Gather: one block per embedding row; row loaded once (L1 for waves 2-4),
// ranks are a single 32B read; stores nontemporal 2KB chunks per batch.
__global__ void __launch_bounds__(256)
k_gather(const uint16_t* __restrict__ rmat,
         const f32x4* __restrict__ emb,
         f32x4* __restrict__ out) {
  __shared__ uint32_t srank[NBATCH];
  const uint32_t idx = blockIdx.x;         // 0..NOBS-1
  const int tid  = threadIdx.x;
  const int w    = tid >> 6;
  const int lane = tid & 63;

  const f32x4* s = emb + (size_t)idx * DIMV;
  const f32x4 v0 = s[lane];
  const f32x4 v1 = s[lane + 64];

  if (tid < NBATCH) srank[tid] = rmat[idx * NBATCH + tid];
  __syncthreads();

#pragma unroll
  for (int j = 0; j < 4; ++j) {
    const int b = w * 4 + j;
    const uint32_t r = srank[b];
    if (r < NTOT) {
      size_t dofs;
      if (r < NSUP) dofs = ((size_t)b * NSUP + r) * DIMV;
      else          dofs = (size_t)NBATCH * NSUP * DIMV
                         + ((size_t)b * NQRY + (size_t)(r - NSUP)) * DIMV;
      f32x4* d = out + dofs;
      __builtin_nontemporal_store(v0, &d[lane]);
      __builtin_nontemporal_store(v1, &d[lane + 64]);
    }
  }
}

extern "C" void kernel_launch(void* const* d_in, const int* in_sizes, int n_in,
                              void* d_out, int out_size, void* d_ws, size_t ws_size,
                              hipStream_t stream) {
  const float* emb = (const float*)d_in[0];

  // ws layout (u32 units):
  uint32_t* hist   = (uint32_t*)d_ws;            // 65536   (256 KB)
  uint32_t* base   = hist + NBATCH * NBINS;      // 65536   (256 KB)
  uint32_t* cursor = base + NBATCH * NBINS;      // 65536   (256 KB)
  uint32_t* bucket = cursor + NBATCH * NBINS;    // 262144  (1 MB)
  uint16_t* rmat   = (uint16_t*)(bucket + NELEM);// 262144 u16 (512 KB)

  void* args[] = { (void*)&hist, (void*)&base, (void*)&cursor,
                   (void*)&bucket, (void*)&rmat };
  hipLaunchCooperativeKernel((const void*)k_setup, dim3(NELEM / 256), dim3(256),
                             args, 0, stream);
  k_gather<<<NOBS, 256, 0, stream>>>(rmat, (const f32x4*)emb, (f32x4*)d_out);
}

// Round 8
// 124.695 us; speedup vs baseline: 3.9774x; 3.9774x over previous
//
#include <hip/hip_runtime.h>
#include <stdint.h>

#define NBATCH 16
#define NOBS   16384     // MAX_DIM (per batch row)
#define NELEM  (NBATCH * NOBS)
#define NSUP   8192
#define NQRY   4096
#define NTOT   12288
#define DIMV   128       // 512 floats = 128 float4
#define NBINS  4096
#define BINSHIFT 11      // 23-bit key >> 11 -> 12-bit bin (avg 4/bin)

typedef float f32x4 __attribute__((ext_vector_type(4)));

__device__ __forceinline__ uint32_t rotl32(uint32_t x, int r) {
  return (x << r) | (x >> (32 - r));
}

// Exact JAX threefry2x32 with key = (0, 42). Verified vs Random123 KAT.
__device__ __forceinline__ void threefry2x32_k42(uint32_t& x0, uint32_t& x1) {
  const uint32_t ks0 = 0u;
  const uint32_t ks1 = 42u;
  const uint32_t ks2 = 0u ^ 42u ^ 0x1BD11BDAu;
  x0 += ks0; x1 += ks1;
#define TF_ROUND(r) { x0 += x1; x1 = rotl32(x1, (r)); x1 ^= x0; }
  TF_ROUND(13) TF_ROUND(15) TF_ROUND(26) TF_ROUND(6)
  x0 += ks1; x1 += ks2 + 1u;
  TF_ROUND(17) TF_ROUND(29) TF_ROUND(16) TF_ROUND(24)
  x0 += ks2; x1 += ks0 + 2u;
  TF_ROUND(13) TF_ROUND(15) TF_ROUND(26) TF_ROUND(6)
  x0 += ks0; x1 += ks1 + 3u;
  TF_ROUND(17) TF_ROUND(29) TF_ROUND(16) TF_ROUND(24)
  x0 += ks1; x1 += ks2 + 4u;
  TF_ROUND(13) TF_ROUND(15) TF_ROUND(26) TF_ROUND(6)
  x0 += ks2; x1 += ks0 + 5u;
#undef TF_ROUND
}

// Partitionable threefry (jax default): counter = (0, flat_index),
// output = x0 ^ x1; key = bits >> 9 (23 mantissa bits, monotone in score).
// [CONFIRMED bit-exact rounds 2-7]
__device__ __forceinline__ uint32_t jax_key(uint32_t f) {
  uint32_t x0 = 0u, x1 = f;
  threefry2x32_k42(x0, x1);
  return (x0 ^ x1) >> 9;
}

// Packed within-bin comparator: (key_low11 << 14) | (16383 - idx).
// Within one bin, q earlier-ranked than m  <=>  packed_q > packed_m.
__device__ __forceinline__ uint32_t pack_cmp(uint32_t key, uint32_t idx_in_row) {
  return ((key & 0x7FFu) << 14) | (16383u - idx_in_row);
}

// Stage 1: per-batch 4096-bin histogram of keys (hist pre-zeroed).
__global__ void __launch_bounds__(256)
k_hist(uint32_t* __restrict__ hist) {
  const uint32_t g = blockIdx.x * 256 + threadIdx.x;   // 0..NELEM-1
  const uint32_t key = jax_key(g);
  atomicAdd(&hist[(g >> 14) * NBINS + (key >> BINSHIFT)], 1u);
}

// Stage 2: per-batch suffix scan -> base (elements in higher bins), cursor=base.
__global__ void __launch_bounds__(1024)
k_scan(const uint32_t* __restrict__ hist,
       uint32_t* __restrict__ base,
       uint32_t* __restrict__ cursor) {
  __shared__ uint32_t s0[NBINS];
  __shared__ uint32_t s1[NBINS];
  const int b   = blockIdx.x;
  const int tid = threadIdx.x;

  uint32_t* src = s0;
  uint32_t* dst = s1;
  for (int i = tid; i < NBINS; i += 1024) src[i] = hist[b * NBINS + i];
  __syncthreads();
  for (int off = 1; off < NBINS; off <<= 1) {
    for (int i = tid; i < NBINS; i += 1024)
      dst[i] = src[i] + ((i + off < NBINS) ? src[i + off] : 0u);
    __syncthreads();
    uint32_t* t = src; src = dst; dst = t;
  }
  for (int i = tid; i < NBINS; i += 1024) {
    const uint32_t v = (i + 1 < NBINS) ? src[i + 1] : 0u;
    base[b * NBINS + i]   = v;
    cursor[b * NBINS + i] = v;
  }
}

// Stage 3: scatter packed comparators into per-batch bucket array.
__global__ void __launch_bounds__(256)
k_scatter(uint32_t* __restrict__ cursor,
          uint32_t* __restrict__ bucket) {
  const uint32_t g   = blockIdx.x * 256 + threadIdx.x;
  const uint32_t b   = g >> 14;
  const uint32_t key = jax_key(g);
  const uint32_t pos = atomicAdd(&cursor[b * NBINS + (key >> BINSHIFT)], 1u);
  bucket[b * NOBS + pos] = pack_cmp(key, g & 16383u);
}

// Stage 4: exact rank -> dense rank matrix rmat[b][idx] (u16, coalesced).
__global__ void __launch_bounds__(256)
k_rank(const uint32_t* __restrict__ hist,
       const uint32_t* __restrict__ base,
       const uint32_t* __restrict__ bucket,
       uint16_t* __restrict__ rmat) {
  const uint32_t g   = blockIdx.x * 256 + threadIdx.x;
  const uint32_t b   = g >> 14;
  const uint32_t idx = g & 16383u;
  const uint32_t key = jax_key(g);
  const uint32_t bin = key >> BINSHIFT;
  const uint32_t me  = pack_cmp(key, idx);
  const uint32_t lob = base[b * NBINS + bin];
  const uint32_t n   = hist[b * NBINS + bin];
  const uint32_t* bk = bucket + b * NOBS + lob;
  uint32_t cnt = 0;
  for (uint32_t q = 0; q < n; ++q) cnt += (bk[q] > me) ? 1u : 0u;
  rmat[b * NOBS + idx] = (uint16_t)(lob + cnt);
}

// Gather: one block per embedding row; row loaded once; ranks are 16
// L2-resident u16 reads; stores nontemporal 2KB chunks per selected batch.
__global__ void __launch_bounds__(256)
k_gather(const uint16_t* __restrict__ rmat,
         const f32x4* __restrict__ emb,
         f32x4* __restrict__ out) {
  __shared__ uint32_t srank[NBATCH];
  const uint32_t idx = blockIdx.x;         // 0..NOBS-1
  const int tid  = threadIdx.x;
  const int w    = tid >> 6;
  const int lane = tid & 63;

  const f32x4* s = emb + (size_t)idx * DIMV;
  const f32x4 v0 = s[lane];
  const f32x4 v1 = s[lane + 64];

  if (tid < NBATCH) srank[tid] = rmat[tid * NOBS + idx];
  __syncthreads();

#pragma unroll
  for (int j = 0; j < 4; ++j) {
    const int b = w * 4 + j;
    const uint32_t r = srank[b];
    if (r < NTOT) {
      size_t dofs;
      if (r < NSUP) dofs = ((size_t)b * NSUP + r) * DIMV;
      else          dofs = (size_t)NBATCH * NSUP * DIMV
                         + ((size_t)b * NQRY + (size_t)(r - NSUP)) * DIMV;
      f32x4* d = out + dofs;
      __builtin_nontemporal_store(v0, &d[lane]);
      __builtin_nontemporal_store(v1, &d[lane + 64]);
    }
  }
}

extern "C" void kernel_launch(void* const* d_in, const int* in_sizes, int n_in,
                              void* d_out, int out_size, void* d_ws, size_t ws_size,
                              hipStream_t stream) {
  const float* emb = (const float*)d_in[0];

  // ws layout (u32 units):
  uint32_t* hist   = (uint32_t*)d_ws;            // 65536   (256 KB)
  uint32_t* base   = hist + NBATCH * NBINS;      // 65536   (256 KB)
  uint32_t* cursor = base + NBATCH * NBINS;      // 65536   (256 KB)
  uint32_t* bucket = cursor + NBATCH * NBINS;    // 262144  (1 MB)
  uint16_t* rmat   = (uint16_t*)(bucket + NELEM);// 262144 u16 (512 KB)

  hipMemsetAsync(hist, 0, NBATCH * NBINS * sizeof(uint32_t), stream);
  k_hist   <<<NELEM / 256, 256, 0, stream>>>(hist);
  k_scan   <<<NBATCH, 1024, 0, stream>>>(hist, base, cursor);
  k_scatter<<<NELEM / 256, 256, 0, stream>>>(cursor, bucket);
  k_rank   <<<NELEM / 256, 256, 0, stream>>>(hist, base, bucket, rmat);
  k_gather <<<NOBS, 256, 0, stream>>>(rmat, (const f32x4*)emb, (f32x4*)d_out);
}

// Round 9
// 110.551 us; speedup vs baseline: 4.4862x; 1.1279x over previous
//
#include <hip/hip_runtime.h>
#include <stdint.h>

#define NBATCH 16
#define NOBS   16384     // MAX_DIM (per batch row)
#define NSUP   8192
#define NQRY   4096
#define NTOT   12288
#define DIMV   128       // 512 floats = 128 float4
#define NBINS  4096
#define BINSHIFT 11      // 23-bit key >> 11 -> 12-bit bin (avg 4/bin)

typedef float f32x4 __attribute__((ext_vector_type(4)));

__device__ __forceinline__ uint32_t rotl32(uint32_t x, int r) {
  return (x << r) | (x >> (32 - r));
}

// Exact JAX threefry2x32 with key = (0, 42). Verified vs Random123 KAT.
__device__ __forceinline__ void threefry2x32_k42(uint32_t& x0, uint32_t& x1) {
  const uint32_t ks0 = 0u;
  const uint32_t ks1 = 42u;
  const uint32_t ks2 = 0u ^ 42u ^ 0x1BD11BDAu;
  x0 += ks0; x1 += ks1;
#define TF_ROUND(r) { x0 += x1; x1 = rotl32(x1, (r)); x1 ^= x0; }
  TF_ROUND(13) TF_ROUND(15) TF_ROUND(26) TF_ROUND(6)
  x0 += ks1; x1 += ks2 + 1u;
  TF_ROUND(17) TF_ROUND(29) TF_ROUND(16) TF_ROUND(24)
  x0 += ks2; x1 += ks0 + 2u;
  TF_ROUND(13) TF_ROUND(15) TF_ROUND(26) TF_ROUND(6)
  x0 += ks0; x1 += ks1 + 3u;
  TF_ROUND(17) TF_ROUND(29) TF_ROUND(16) TF_ROUND(24)
  x0 += ks1; x1 += ks2 + 4u;
  TF_ROUND(13) TF_ROUND(15) TF_ROUND(26) TF_ROUND(6)
  x0 += ks2; x1 += ks0 + 5u;
#undef TF_ROUND
}

// Partitionable threefry (jax default): counter = (0, flat_index),
// output = x0 ^ x1; key = bits >> 9 (23 mantissa bits, monotone in score).
// [CONFIRMED bit-exact rounds 2-8]
__device__ __forceinline__ uint32_t jax_key(uint32_t f) {
  uint32_t x0 = 0u, x1 = f;
  threefry2x32_k42(x0, x1);
  return (x0 ^ x1) >> 9;
}

// Packed within-bin comparator: (key_low11 << 14) | (16383 - idx).
// Within one bin, q earlier-ranked than m  <=>  packed_q > packed_m.
__device__ __forceinline__ uint32_t pack_cmp(uint32_t key, uint32_t idx_in_row) {
  return ((key & 0x7FFu) << 14) | (16383u - idx_in_row);
}

// Monolithic ranking: one block per batch row, every phase in LDS.
// Phases: zero-hist -> hist (LDS atomics) -> two-level wave-shuffle suffix
// scan -> bucket scatter -> exact within-bin rank -> rmat[idx][b] (u16).
__global__ void __launch_bounds__(1024)
k_rank16(uint16_t* __restrict__ rmat) {
  __shared__ uint32_t bucket[NOBS];    // 64 KB (packed cmp values)
  __shared__ uint32_t hist[NBINS];     // 16 KB
  __shared__ uint32_t base[NBINS];     // 16 KB
  __shared__ uint32_t cursor[NBINS];   // 16 KB   (total 112 KB)
  __shared__ uint32_t wtot[16];
  __shared__ uint32_t wafter[16];

  const int b    = blockIdx.x;
  const int tid  = threadIdx.x;
  const int wid  = tid >> 6;
  const int lane = tid & 63;

  // ---- phase 0: zero hist (4 contiguous bins per thread) ----
#pragma unroll
  for (int k = 0; k < 4; ++k) hist[tid * 4 + k] = 0u;
  __syncthreads();

  // ---- phase 1: keys + histogram ----
  uint32_t key[16];
#pragma unroll
  for (int i = 0; i < 16; ++i) {
    key[i] = jax_key((uint32_t)(b * NOBS + i * 1024 + tid));
    atomicAdd(&hist[key[i] >> BINSHIFT], 1u);
  }
  __syncthreads();

  // ---- phase 2: suffix scan (thread t owns bins 4t..4t+3) ----
  const uint32_t c0 = hist[tid * 4 + 0];
  const uint32_t c1 = hist[tid * 4 + 1];
  const uint32_t c2 = hist[tid * 4 + 2];
  const uint32_t c3 = hist[tid * 4 + 3];
  const uint32_t s  = c0 + c1 + c2 + c3;
  // within-wave inclusive suffix scan of per-thread sums
  uint32_t v = s;
#pragma unroll
  for (int off = 1; off < 64; off <<= 1) {
    const uint32_t nb = __shfl_down(v, off);
    v += (lane + off < 64) ? nb : 0u;
  }
  if (lane == 0) wtot[wid] = v;      // wave total
  __syncthreads();
  if (wid == 0) {                    // all 64 lanes active (no divergent shfl)
    const uint32_t t = (lane < 16) ? wtot[lane] : 0u;
    uint32_t u = t;
#pragma unroll
    for (int off = 1; off < 16; off <<= 1) {
      const uint32_t nb = __shfl_down(u, off);
      u += (lane + off < 64) ? nb : 0u;
    }
    if (lane < 16) wafter[lane] = u - t;   // waves strictly after mine
  }
  __syncthreads();
  const uint32_t after = (v - s) + wafter[wid];  // elems in threads > tid
  // base[bin] = #elements in strictly-higher bins
  base[tid * 4 + 3] = after;
  base[tid * 4 + 2] = after + c3;
  base[tid * 4 + 1] = after + c3 + c2;
  base[tid * 4 + 0] = after + c3 + c2 + c1;
  cursor[tid * 4 + 3] = after;
  cursor[tid * 4 + 2] = after + c3;
  cursor[tid * 4 + 1] = after + c3 + c2;
  cursor[tid * 4 + 0] = after + c3 + c2 + c1;
  __syncthreads();

  // ---- phase 3: bucket scatter ----
  uint32_t me[16];
#pragma unroll
  for (int i = 0; i < 16; ++i) {
    me[i] = pack_cmp(key[i], (uint32_t)(i * 1024 + tid));
    const uint32_t pos = atomicAdd(&cursor[key[i] >> BINSHIFT], 1u);
    bucket[pos] = me[i];
  }
  __syncthreads();

  // ---- phase 4: exact rank -> rmat[idx][b] ----
#pragma unroll 1
  for (int i = 0; i < 16; ++i) {
    const uint32_t bin = key[i] >> BINSHIFT;
    const uint32_t lob = base[bin];
    const uint32_t n   = hist[bin];
    uint32_t cnt = 0;
    for (uint32_t q = 0; q < n; ++q) cnt += (bucket[lob + q] > me[i]) ? 1u : 0u;
    rmat[(size_t)(i * 1024 + tid) * NBATCH + b] = (uint16_t)(lob + cnt);
  }
}

// Gather: one block per embedding row; row loaded once; ranks = one 32B
// line; PLAIN stores (same L2 write path as the 6.9 TB/s harness fill).
__global__ void __launch_bounds__(256)
k_gather(const uint16_t* __restrict__ rmat,
         const f32x4* __restrict__ emb,
         f32x4* __restrict__ out) {
  __shared__ uint32_t srank[NBATCH];
  const uint32_t idx = blockIdx.x;         // 0..NOBS-1
  const int tid  = threadIdx.x;
  const int w    = tid >> 6;
  const int lane = tid & 63;

  const f32x4* s = emb + (size_t)idx * DIMV;
  const f32x4 v0 = s[lane];
  const f32x4 v1 = s[lane + 64];

  if (tid < NBATCH) srank[tid] = rmat[(size_t)idx * NBATCH + tid];
  __syncthreads();

#pragma unroll
  for (int j = 0; j < 4; ++j) {
    const int b = w * 4 + j;
    const uint32_t r = srank[b];
    if (r < NTOT) {
      size_t dofs;
      if (r < NSUP) dofs = ((size_t)b * NSUP + r) * DIMV;
      else          dofs = (size_t)NBATCH * NSUP * DIMV
                         + ((size_t)b * NQRY + (size_t)(r - NSUP)) * DIMV;
      f32x4* d = out + dofs;
      d[lane]      = v0;
      d[lane + 64] = v1;
    }
  }
}

extern "C" void kernel_launch(void* const* d_in, const int* in_sizes, int n_in,
                              void* d_out, int out_size, void* d_ws, size_t ws_size,
                              hipStream_t stream) {
  const float* emb = (const float*)d_in[0];
  uint16_t* rmat = (uint16_t*)d_ws;   // NOBS*NBATCH u16 = 512 KB

  k_rank16<<<NBATCH, 1024, 0, stream>>>(rmat);
  k_gather<<<NOBS, 256, 0, stream>>>(rmat, (const f32x4*)emb, (f32x4*)d_out);
}

// Round 11
// 108.808 us; speedup vs baseline: 4.5581x; 1.0160x over previous
//
#include <hip/hip_runtime.h>
#include <stdint.h>

#define NBATCH 16
#define NOBS   16384     // MAX_DIM (per batch row)
#define NSUP   8192
#define NQRY   4096
#define NTOT   12288
#define DIMV   128       // 512 floats = 128 float4
#define NBINS  4096
#define BINSHIFT 11      // 23-bit key >> 11 -> 12-bit bin (avg 4/bin)

typedef float f32x4 __attribute__((ext_vector_type(4)));

__device__ __forceinline__ uint32_t rotl32(uint32_t x, int r) {
  return (x << r) | (x >> (32 - r));
}

// Exact JAX threefry2x32 with key = (0, 42). Verified vs Random123 KAT.
__device__ __forceinline__ void threefry2x32_k42(uint32_t& x0, uint32_t& x1) {
  const uint32_t ks0 = 0u;
  const uint32_t ks1 = 42u;
  const uint32_t ks2 = 0u ^ 42u ^ 0x1BD11BDAu;
  x0 += ks0; x1 += ks1;
#define TF_ROUND(r) { x0 += x1; x1 = rotl32(x1, (r)); x1 ^= x0; }
  TF_ROUND(13) TF_ROUND(15) TF_ROUND(26) TF_ROUND(6)
  x0 += ks1; x1 += ks2 + 1u;
  TF_ROUND(17) TF_ROUND(29) TF_ROUND(16) TF_ROUND(24)
  x0 += ks2; x1 += ks0 + 2u;
  TF_ROUND(13) TF_ROUND(15) TF_ROUND(26) TF_ROUND(6)
  x0 += ks0; x1 += ks1 + 3u;
  TF_ROUND(17) TF_ROUND(29) TF_ROUND(16) TF_ROUND(24)
  x0 += ks1; x1 += ks2 + 4u;
  TF_ROUND(13) TF_ROUND(15) TF_ROUND(26) TF_ROUND(6)
  x0 += ks2; x1 += ks0 + 5u;
#undef TF_ROUND
}

// Partitionable threefry (jax default): counter = (0, flat_index),
// output = x0 ^ x1; key = bits >> 9 (23 mantissa bits, monotone in score).
// [CONFIRMED bit-exact rounds 2-9]
__device__ __forceinline__ uint32_t jax_key(uint32_t f) {
  uint32_t x0 = 0u, x1 = f;
  threefry2x32_k42(x0, x1);
  return (x0 ^ x1) >> 9;
}

// Packed within-bin comparator: (key_low11 << 14) | (16383 - idx).
// Within one bin, q earlier-ranked than m  <=>  packed_q > packed_m.
__device__ __forceinline__ uint32_t pack_cmp(uint32_t key, uint32_t idx_in_row) {
  return ((key & 0x7FFu) << 14) | (16383u - idx_in_row);
}

// Prep: one block per batch. LDS hist -> wave-shuffle suffix scan ->
// LDS bucket scatter; emits meta[b][bin] = (base<<16)|cnt and the
// bucket array (packed cmp values, bin-grouped) to global.
__global__ void __launch_bounds__(1024)
k_prep(uint32_t* __restrict__ meta_g, uint32_t* __restrict__ bucket_g) {
  __shared__ uint32_t bucket[NOBS];    // 64 KB
  __shared__ uint32_t hist[NBINS];     // 16 KB
  __shared__ uint32_t cursor[NBINS];   // 16 KB
  __shared__ uint32_t wtot[16];
  __shared__ uint32_t wafter[16];

  const int b    = blockIdx.x;
  const int tid  = threadIdx.x;
  const int wid  = tid >> 6;
  const int lane = tid & 63;

#pragma unroll
  for (int k = 0; k < 4; ++k) hist[tid * 4 + k] = 0u;
  __syncthreads();

  uint32_t key[16];
#pragma unroll
  for (int i = 0; i < 16; ++i) {
    key[i] = jax_key((uint32_t)(b * NOBS + i * 1024 + tid));
    atomicAdd(&hist[key[i] >> BINSHIFT], 1u);
  }
  __syncthreads();

  // suffix scan (thread t owns bins 4t..4t+3)
  const uint32_t c0 = hist[tid * 4 + 0];
  const uint32_t c1 = hist[tid * 4 + 1];
  const uint32_t c2 = hist[tid * 4 + 2];
  const uint32_t c3 = hist[tid * 4 + 3];
  const uint32_t s  = c0 + c1 + c2 + c3;
  uint32_t v = s;
#pragma unroll
  for (int off = 1; off < 64; off <<= 1) {
    const uint32_t nb = __shfl_down(v, off);
    v += (lane + off < 64) ? nb : 0u;
  }
  if (lane == 0) wtot[wid] = v;
  __syncthreads();
  if (wid == 0) {
    const uint32_t t = (lane < 16) ? wtot[lane] : 0u;
    uint32_t u = t;
#pragma unroll
    for (int off = 1; off < 16; off <<= 1) {
      const uint32_t nb = __shfl_down(u, off);
      u += (lane + off < 64) ? nb : 0u;
    }
    if (lane < 16) wafter[lane] = u - t;
  }
  __syncthreads();
  const uint32_t after = (v - s) + wafter[wid];
  const uint32_t b3 = after;
  const uint32_t b2 = after + c3;
  const uint32_t b1 = after + c3 + c2;
  const uint32_t b0 = after + c3 + c2 + c1;
  cursor[tid * 4 + 0] = b0;
  cursor[tid * 4 + 1] = b1;
  cursor[tid * 4 + 2] = b2;
  cursor[tid * 4 + 3] = b3;
  // meta = (base<<16) | cnt   (base <= 16384 fits; cnt <= 16384 fits)
  uint32_t* mo = meta_g + (size_t)b * NBINS + tid * 4;
  mo[0] = (b0 << 16) | c0;
  mo[1] = (b1 << 16) | c1;
  mo[2] = (b2 << 16) | c2;
  mo[3] = (b3 << 16) | c3;
  __syncthreads();

  // bucket scatter in LDS, then coalesced copy to global
#pragma unroll
  for (int i = 0; i < 16; ++i) {
    const uint32_t me  = pack_cmp(key[i], (uint32_t)(i * 1024 + tid));
    const uint32_t pos = atomicAdd(&cursor[key[i] >> BINSHIFT], 1u);
    bucket[pos] = me;
  }
  __syncthreads();
  uint32_t* bo = bucket_g + (size_t)b * NOBS;
#pragma unroll
  for (int i = 0; i < 16; ++i) bo[i * 1024 + tid] = bucket[i * 1024 + tid];
}

// Gather: one block per embedding row. Lanes 0..15 recompute their key,
// read meta + avg-4-entry bucket run, rank in-block (hidden under the
// write-bound store stream); 4 waves store 2KB chunks to selected batches.
__global__ void __launch_bounds__(256)
k_gather(const uint32_t* __restrict__ meta_g,
         const uint32_t* __restrict__ bucket_g,
         const f32x4* __restrict__ emb,
         f32x4* __restrict__ out) {
  __shared__ uint32_t srank[NBATCH];
  const uint32_t idx = blockIdx.x;         // 0..NOBS-1
  const int tid  = threadIdx.x;
  const int w    = tid >> 6;
  const int lane = tid & 63;

  const f32x4* s = emb + (size_t)idx * DIMV;
  const f32x4 v0 = s[lane];
  const f32x4 v1 = s[lane + 64];

  if (tid < NBATCH) {
    const uint32_t b    = (uint32_t)tid;
    const uint32_t key  = jax_key(b * NOBS + idx);
    const uint32_t bin  = key >> BINSHIFT;
    const uint32_t meta = meta_g[b * NBINS + bin];
    const uint32_t lob  = meta >> 16;
    const uint32_t n    = meta & 0xFFFFu;
    const uint32_t me   = pack_cmp(key, idx);
    const uint32_t* bk  = bucket_g + b * NOBS + lob;
    uint32_t cnt = 0;
    for (uint32_t q = 0; q < n; ++q) cnt += (bk[q] > me) ? 1u : 0u;
    srank[b] = lob + cnt;
  }
  __syncthreads();

#pragma unroll
  for (int j = 0; j < 4; ++j) {
    const int b = w * 4 + j;
    const uint32_t r = srank[b];
    if (r < NTOT) {
      size_t dofs;
      if (r < NSUP) dofs = ((size_t)b * NSUP + r) * DIMV;
      else          dofs = (size_t)NBATCH * NSUP * DIMV
                         + ((size_t)b * NQRY + (size_t)(r - NSUP)) * DIMV;
      f32x4* d = out + dofs;
      d[lane]      = v0;
      d[lane + 64] = v1;
    }
  }
}

extern "C" void kernel_launch(void* const* d_in, const int* in_sizes, int n_in,
                              void* d_out, int out_size, void* d_ws, size_t ws_size,
                              hipStream_t stream) {
  const float* emb = (const float*)d_in[0];

  uint32_t* meta   = (uint32_t*)d_ws;                 // 16*4096 u32 = 256 KB
  uint32_t* bucket = meta + NBATCH * NBINS;           // 16*16384 u32 = 1 MB

  k_prep  <<<NBATCH, 1024, 0, stream>>>(meta, bucket);
  k_gather<<<NOBS, 256, 0, stream>>>(meta, bucket, (const f32x4*)emb,
                                     (f32x4*)d_out);
}